// Round 6
// baseline (1084.493 us; speedup 1.0000x reference)
//
#include <hip/hip_runtime.h>
#include <hip/hip_bf16.h>
#include <stddef.h>

#define BATCH 16
#define CH    256
#define NPIX  4096
#define DQH   64
#define L2E   1.44269504088896340736f

typedef __attribute__((ext_vector_type(8))) short bf16x8;
typedef __attribute__((ext_vector_type(4))) float floatx4;

__device__ __forceinline__ unsigned short f2bf(float f) {
  union { float f; unsigned int u; } v; v.f = f;
  unsigned int u = v.u;
  u += 0x7fffu + ((u >> 16) & 1u);   // RNE
  return (unsigned short)(u >> 16);
}

__device__ __forceinline__ unsigned int pk2bf(float a, float b) {
  __hip_bfloat162 h = __float22bfloat162_rn(float2{a, b});
  union { __hip_bfloat162 h; unsigned int u; } cv;
  cv.h = h;
  return cv.u;
}

__device__ __forceinline__ bf16x8 ldbf8(const unsigned short* p) {
  return *(const bf16x8*)p;
}

// XCD-aware bijective work swizzle (nwg % 8 == 0).
__device__ __forceinline__ int xcd_swz(int lin, int nwg) {
  return (lin & 7) * (nwg >> 3) + (lin >> 3);
}

// async global->LDS, 16B per lane. LDS dest = wave-uniform base + lane*16.
__device__ __forceinline__ void gload_lds16(const void* g, void* l) {
  __builtin_amdgcn_global_load_lds(
      (const __attribute__((address_space(1))) void*)g,
      (__attribute__((address_space(3))) void*)l, 16, 0, 0);
}

// ---------------------------------------------------------------------------
// Kernel 0: convert W matrices to bf16. Wq rows pre-scaled by log2(e) so the
// QK^T MFMA emits E directly in log2 units.
// ---------------------------------------------------------------------------
__global__ __launch_bounds__(256) void wconv_kernel(
    const float* __restrict__ Wq, const float* __restrict__ Wk,
    const float* __restrict__ Wv, unsigned short* __restrict__ Wb) {
  const int idx = blockIdx.x * 256 + threadIdx.x;   // < 98304
  float v;
  if (idx < 64 * CH)            v = Wq[idx] * L2E;
  else if (idx < 128 * CH)      v = Wk[idx - 64 * CH];
  else                          v = Wv[idx - 128 * CH];
  Wb[idx] = f2bf(v);
}

// ---------------------------------------------------------------------------
// Kernel 1: QKV projection GEMM (unchanged; frozen to isolate pass2 change).
// ---------------------------------------------------------------------------
__global__ __launch_bounds__(256) void proj_kernel(
    const float* __restrict__ xq, const float* __restrict__ xk,
    const float* __restrict__ xv, const unsigned short* __restrict__ Wb,
    const float* __restrict__ bq, const float* __restrict__ bk,
    const float* __restrict__ bv,
    unsigned short* __restrict__ Qb, unsigned short* __restrict__ Kb,
    unsigned short* __restrict__ Vb) {
  __shared__ __attribute__((aligned(16))) float xtile[32][256];  // 32 KB
  const int t    = threadIdx.x;
  const int lane = t & 63;
  const int w    = t >> 6;
  const int l15  = lane & 15;
  const int quad = lane >> 4;
  const int b    = blockIdx.y;
  const int pxbase = blockIdx.x * 256;
  const int z    = blockIdx.z;

  const float* X; const float* bt; int dbase; int wbase;
  if (z == 0)      { X = xq; bt = bq; dbase = 0;            wbase = 0; }
  else if (z == 1) { X = xk; bt = bk; dbase = 0;            wbase = 64; }
  else             { X = xv; bt = bv; dbase = (z - 2) * 64; wbase = 128 + (z - 2) * 64; }

  floatx4 acc[4][4];
#pragma unroll
  for (int mt = 0; mt < 4; ++mt)
#pragma unroll
    for (int nt = 0; nt < 4; ++nt)
      acc[mt][nt] = (floatx4){0.f, 0.f, 0.f, 0.f};

  const float* xb0 = X + (size_t)b * CH * NPIX + pxbase;

  for (int kb = 0; kb < 8; ++kb) {
    // stage 32 rows x 256 px fp32 -> LDS via async DMA; source pre-rotated
#pragma unroll
    for (int i = 0; i < 8; ++i) {
      const int cloc = w + i * 4;                       // wave-uniform row
      const int rot  = (cloc >> 3) << 3;                // 8*(row/8) floats
      const int colf = ((lane << 2) - rot) & 255;       // per-lane source col
      gload_lds16(xb0 + (size_t)(kb * 32 + cloc) * NPIX + colf,
                  &xtile[cloc][0]);
    }
    __syncthreads();   // drains vmcnt -> xtile ready

#pragma unroll
    for (int nt = 0; nt < 4; ++nt) {
      // B fragment: pixel = w*64 + nt*16 + l15, k = quad*8 + j
      const int pxl = w * 64 + nt * 16 + l15;
      float f[8];
#pragma unroll
      for (int j = 0; j < 8; ++j) {
        const int row = quad * 8 + j;
        f[j] = xtile[row][(pxl + ((row >> 3) << 3)) & 255];
      }
      union { bf16x8 v; unsigned int u[4]; } bb;
      bb.u[0] = pk2bf(f[0], f[1]);
      bb.u[1] = pk2bf(f[2], f[3]);
      bb.u[2] = pk2bf(f[4], f[5]);
      bb.u[3] = pk2bf(f[6], f[7]);
#pragma unroll
      for (int mt = 0; mt < 4; ++mt) {
        const bf16x8 aA =
            ldbf8(Wb + (size_t)(wbase + mt * 16 + l15) * CH + kb * 32 + quad * 8);
        acc[mt][nt] =
            __builtin_amdgcn_mfma_f32_16x16x32_bf16(aA, bb.v, acc[mt][nt], 0, 0, 0);
      }
    }
    __syncthreads();
  }

  // epilogue: C-layout col=l15 (pixel), row=quad*4+r (outch)
  float4 bias4[4];
#pragma unroll
  for (int mt = 0; mt < 4; ++mt)
    bias4[mt] = *(const float4*)&bt[dbase + mt * 16 + quad * 4];
  if (z == 0) {
#pragma unroll
    for (int mt = 0; mt < 4; ++mt) {
      bias4[mt].x *= L2E; bias4[mt].y *= L2E;
      bias4[mt].z *= L2E; bias4[mt].w *= L2E;
    }
  }

  if (z >= 2) {
    // V layout [b][c][pixel]
#pragma unroll
    for (int mt = 0; mt < 4; ++mt)
#pragma unroll
      for (int nt = 0; nt < 4; ++nt) {
        const int px = pxbase + w * 64 + nt * 16 + l15;
#pragma unroll
        for (int r = 0; r < 4; ++r) {
          const int c = dbase + mt * 16 + quad * 4 + r;
          Vb[((size_t)b * CH + c) * NPIX + px] =
              f2bf(acc[mt][nt][r] + ((const float*)&bias4[mt])[r]);
        }
      }
  } else {
    // Q/K layout [b][pixel][d]
    unsigned short* Ob = (z == 0) ? Qb : Kb;
#pragma unroll
    for (int mt = 0; mt < 4; ++mt)
#pragma unroll
      for (int nt = 0; nt < 4; ++nt) {
        const int px = pxbase + w * 64 + nt * 16 + l15;
        uint2 qp;
        qp.x = pk2bf(acc[mt][nt][0] + ((const float*)&bias4[mt])[0],
                     acc[mt][nt][1] + ((const float*)&bias4[mt])[1]);
        qp.y = pk2bf(acc[mt][nt][2] + ((const float*)&bias4[mt])[2],
                     acc[mt][nt][3] + ((const float*)&bias4[mt])[3]);
        *(uint2*)&Ob[((size_t)b * NPIX + px) * DQH + mt * 16 + quad * 4] = qp;
      }
  }
}

// ---------------------------------------------------------------------------
// Kernel 2: per-row softmax stats, max-free in log2 domain (unchanged).
// ---------------------------------------------------------------------------
__global__ __launch_bounds__(256) void pass1_kernel(
    const unsigned short* __restrict__ Qb, const unsigned short* __restrict__ Kb,
    float* __restrict__ Srow) {
  const int t    = threadIdx.x;
  const int lane = t & 63;
  const int w    = t >> 6;
  const int l15  = lane & 15;
  const int quad = lane >> 4;
  const int lin  = blockIdx.x + (blockIdx.y << 6);      // grid (64,16)
  const int swz  = xcd_swz(lin, 64 * BATCH);
  const int b     = swz >> 6;
  const int jbase = (swz & 63) * 64 + w * 16;

  const unsigned short* qrow = Qb + ((size_t)b * NPIX + jbase + l15) * DQH;
  const bf16x8 qA0 = ldbf8(qrow + quad * 8);
  const bf16x8 qA1 = ldbf8(qrow + 32 + quad * 8);

  float lsum[4] = {0.f, 0.f, 0.f, 0.f};

  const unsigned short* kbase = Kb + (size_t)b * NPIX * DQH;

  bf16x8 kC[4][2], kN[4][2];
#pragma unroll
  for (int nt = 0; nt < 4; ++nt) {
    const unsigned short* krow = kbase + (size_t)(nt * 16 + l15) * DQH;
    kC[nt][0] = ldbf8(krow + quad * 8);
    kC[nt][1] = ldbf8(krow + 32 + quad * 8);
  }

  for (int ib = 0; ib < NPIX; ib += 64) {
    const int in = (ib + 64) & (NPIX - 1);   // wraps on last iter (unused)
#pragma unroll
    for (int nt = 0; nt < 4; ++nt) {
      const unsigned short* krow = kbase + (size_t)(in + nt * 16 + l15) * DQH;
      kN[nt][0] = ldbf8(krow + quad * 8);
      kN[nt][1] = ldbf8(krow + 32 + quad * 8);
    }
#pragma unroll
    for (int nt = 0; nt < 4; ++nt) {
      floatx4 a = {0.f, 0.f, 0.f, 0.f};
      a = __builtin_amdgcn_mfma_f32_16x16x32_bf16(qA0, kC[nt][0], a, 0, 0, 0);
      a = __builtin_amdgcn_mfma_f32_16x16x32_bf16(qA1, kC[nt][1], a, 0, 0, 0);
#pragma unroll
      for (int r = 0; r < 4; ++r) lsum[r] += exp2f(a[r]);
    }
#pragma unroll
    for (int nt = 0; nt < 4; ++nt) {
      kC[nt][0] = kN[nt][0];
      kC[nt][1] = kN[nt][1];
    }
  }

#pragma unroll
  for (int r = 0; r < 4; ++r) {
    float s = lsum[r];
    s += __shfl_xor(s, 1);
    s += __shfl_xor(s, 2);
    s += __shfl_xor(s, 4);
    s += __shfl_xor(s, 8);
    if (l15 == 0)
      Srow[(size_t)b * NPIX + jbase + quad * 4 + r] = log2f(s);
  }
}

// ---------------------------------------------------------------------------
// Kernel 3: out[:, i-tile] = sum_j 2^{E'[j,i]-s'_j} * v[:,j].
// r3 skeleton (40->24 MFMA per barrier-pair per wave) + r5's validated
// swizzle/DMA pieces + register-pressure fix:
//  - grid (64,16,2): z halves channels -> accO[4][2] (32 acc regs). E phase
//    duplicated per z (+34 GF total, ~15 us) buys 5 waves/SIMD at
//    launch_bounds(256,5) (r3 was ~124 regs -> 4 waves -> 44% occ).
//  - Qlds double-buffered [2][64][64] staged by global_load_lds, DMA issued
//    at loop TOP (drained by bar2, ~600cyc later -> hidden; r5 exposed it).
//  - T2 XOR swizzle on Qlds (via pre-swizzled DMA source) and Plds
//    (write+read) -> 2-way-max bank access (free per m136).
//  - LDS 24 KB, 2 barriers/iter, V loads inline in PV (r3-proven).
// ---------------------------------------------------------------------------
__global__ __launch_bounds__(256, 5) void pass2_kernel(
    const unsigned short* __restrict__ Qb, const unsigned short* __restrict__ Kb,
    const unsigned short* __restrict__ Vb, const float* __restrict__ Srow,
    float* __restrict__ out) {
  __shared__ __attribute__((aligned(16))) unsigned short Qlds[2][64][64]; // 16 KB
  __shared__ __attribute__((aligned(16))) unsigned short Plds[64][64];    // 8 KB
  const int t    = threadIdx.x;
  const int lane = t & 63;
  const int w    = t >> 6;
  const int l15  = lane & 15;
  const int quad = lane >> 4;
  const int lin  = blockIdx.x + (blockIdx.y << 6);      // 0..1023
  const int swz  = xcd_swz(lin, 64 * BATCH);
  const int b     = swz >> 6;
  const int ibase = (swz & 63) * 64;
  const int cw    = blockIdx.z * 128 + (w >> 1) * 64;   // PV: wave c-base
  const int iloc  = (w & 1) * 32;                       // PV: wave i-offset

  // K fragments for E (rows ibase + w*16 + l15), loaded once
  const unsigned short* krow = Kb + ((size_t)b * NPIX + ibase + w * 16 + l15) * DQH;
  const bf16x8 kB0 = ldbf8(krow + quad * 8);
  const bf16x8 kB1 = ldbf8(krow + 32 + quad * 8);

  floatx4 accO[4][2];
#pragma unroll
  for (int mt = 0; mt < 4; ++mt)
#pragma unroll
    for (int nt = 0; nt < 2; ++nt)
      accO[mt][nt] = (floatx4){0.f, 0.f, 0.f, 0.f};

  const float* sp          = Srow + (size_t)b * NPIX;
  const unsigned short* qb = Qb + (size_t)b * NPIX * DQH;
  const unsigned short* vb = Vb + (size_t)b * CH * NPIX;

  // Q DMA geometry: 2 shots x 4KB. Thread t covers row t>>3 (and +32),
  // 16B segment t&7, swizzle folded into SOURCE (LDS write linear):
  // src short-offset = ((seg ^ (row&7)) << 3); (row&7) identical for row,row+32.
  const int qrw  = t >> 3;                        // 0..31
  const int qsof = (((t & 7) ^ (qrw & 7)) << 3);  // shorts within row
  // wave-uniform LDS dests: shot A rows [w*8, w*8+8), shot B +32.

  // prologue: stage Q tile jb=0 into buf 0
  gload_lds16(qb + (size_t)qrw * DQH + qsof,        &Qlds[0][w * 8][0]);
  gload_lds16(qb + (size_t)(32 + qrw) * DQH + qsof, &Qlds[0][32 + w * 8][0]);
  __syncthreads();

  int cur = 0;
  for (int jb = 0; jb < NPIX; jb += 64) {
    // issue next-tile Q DMA into buf^1 (drained by bar2, ~600cyc away)
    const int jn = (jb + 64) & (NPIX - 1);        // wraps on last iter (unused)
    gload_lds16(qb + (size_t)(jn + qrw) * DQH + qsof,
                &Qlds[cur ^ 1][w * 8][0]);
    gload_lds16(qb + (size_t)(jn + 32 + qrw) * DQH + qsof,
                &Qlds[cur ^ 1][32 + w * 8][0]);

    // ---- E phase: P[i = w*16 strip][j = 0..64] (4 waves cover 64 i) ----
#pragma unroll
    for (int jt = 0; jt < 4; ++jt) {
      const int qr = jt * 16 + l15;               // Q row (j)
      const int qx = (qr & 7) << 4;
      const bf16x8 q0 =
          *(const bf16x8*)((const char*)&Qlds[cur][qr][0] + ((quad * 16) ^ qx));
      const bf16x8 q1 =
          *(const bf16x8*)((const char*)&Qlds[cur][qr][0] + ((64 + quad * 16) ^ qx));
      floatx4 a = {0.f, 0.f, 0.f, 0.f};
      a = __builtin_amdgcn_mfma_f32_16x16x32_bf16(q0, kB0, a, 0, 0, 0);
      a = __builtin_amdgcn_mfma_f32_16x16x32_bf16(q1, kB1, a, 0, 0, 0);
      const float4 s4 = *(const float4*)&sp[jb + jt * 16 + quad * 4];
      uint2 pk;
      pk.x = pk2bf(exp2f(a[0] - s4.x), exp2f(a[1] - s4.y));
      pk.y = pk2bf(exp2f(a[2] - s4.z), exp2f(a[3] - s4.w));
      const int pr = w * 16 + l15;                // P row (i)
      *(uint2*)((char*)&Plds[pr][0] +
                ((jt * 32 + quad * 8) ^ ((pr & 7) << 4))) = pk;
    }
    __syncthreads();   // bar1: P complete, Qlds[cur] reads complete

    // ---- PV: acc[c, i] += V[c, jb..jb+64] * P (wave: 64c x 32i) ----
#pragma unroll
    for (int ks = 0; ks < 2; ++ks) {
      bf16x8 pB[2];
#pragma unroll
      for (int nt = 0; nt < 2; ++nt) {
        const int br = iloc + nt * 16 + l15;
        pB[nt] = *(const bf16x8*)((const char*)&Plds[br][0] +
                                  ((ks * 64 + quad * 16) ^ ((br & 7) << 4)));
      }
#pragma unroll
      for (int mt = 0; mt < 4; ++mt) {
        const bf16x8 vA = ldbf8(vb + (size_t)(cw + mt * 16 + l15) * NPIX +
                                jb + ks * 32 + quad * 8);
#pragma unroll
        for (int nt = 0; nt < 2; ++nt)
          accO[mt][nt] = __builtin_amdgcn_mfma_f32_16x16x32_bf16(
              vA, pB[nt], accO[mt][nt], 0, 0, 0);
      }
    }
    __syncthreads();   // bar2: Plds reads done; Q DMA drained -> flip
    cur ^= 1;
  }

#pragma unroll
  for (int mt = 0; mt < 4; ++mt) {
#pragma unroll
    for (int nt = 0; nt < 2; ++nt) {
#pragma unroll
      for (int r = 0; r < 4; ++r) {
        const int c = cw + mt * 16 + quad * 4 + r;
        const int i = ibase + iloc + nt * 16 + l15;
        out[((size_t)b * CH + c) * NPIX + i] = accO[mt][nt][r];
      }
    }
  }
}

// ---------------------------------------------------------------------------
extern "C" void kernel_launch(void* const* d_in, const int* in_sizes, int n_in,
                              void* d_out, int out_size, void* d_ws, size_t ws_size,
                              hipStream_t stream) {
  (void)in_sizes; (void)n_in; (void)out_size; (void)ws_size;
  const float* xq = (const float*)d_in[0];
  const float* xk = (const float*)d_in[1];
  const float* xv = (const float*)d_in[2];
  const float* Wq = (const float*)d_in[3];
  const float* bq = (const float*)d_in[4];
  const float* Wk = (const float*)d_in[5];
  const float* bk = (const float*)d_in[6];
  const float* Wv = (const float*)d_in[7];
  const float* bv = (const float*)d_in[8];
  float* out = (float*)d_out;

  // workspace layout (bytes):
  //   Qb bf16 [16][4096][64]   @ 0          (8 MiB)   (pre-scaled by log2(e))
  //   Kb bf16 [16][4096][64]   @ 8 MiB      (8 MiB)
  //   Vb bf16 [16][256][4096]  @ 16 MiB     (32 MiB)
  //   Srow f32 [16][4096]      @ 48 MiB     (256 KiB) (log2-domain LSE)
  //   Wb bf16 [384][256]       @ 48.25 MiB  (192 KiB)
  char* ws = (char*)d_ws;
  const size_t qk_bytes = (size_t)BATCH * NPIX * DQH * 2;   // 8 MiB
  const size_t v_bytes  = (size_t)BATCH * CH * NPIX * 2;    // 32 MiB
  const size_t s_bytes  = (size_t)BATCH * NPIX * 4;         // 256 KiB
  unsigned short* Qb = (unsigned short*)(ws);
  unsigned short* Kb = (unsigned short*)(ws + qk_bytes);
  unsigned short* Vb = (unsigned short*)(ws + 2 * qk_bytes);
  float* Srow        = (float*)(ws + 2 * qk_bytes + v_bytes);
  unsigned short* Wb = (unsigned short*)(ws + 2 * qk_bytes + v_bytes + s_bytes);

  wconv_kernel<<<dim3(384), 256, 0, stream>>>(Wq, Wk, Wv, Wb);
  proj_kernel<<<dim3(16, 16, 6), 256, 0, stream>>>(xq, xk, xv, Wb, bq, bk, bv,
                                                   Qb, Kb, Vb);
  pass1_kernel<<<dim3(64, 16), 256, 0, stream>>>(Qb, Kb, Srow);
  pass2_kernel<<<dim3(64, 16, 2), 256, 0, stream>>>(Qb, Kb, Vb, Srow, out);
}

// Round 7
// 758.964 us; speedup vs baseline: 1.4289x; 1.4289x over previous
//
#include <hip/hip_runtime.h>
#include <hip/hip_bf16.h>
#include <stddef.h>

#define BATCH 16
#define CH    256
#define NPIX  4096
#define DQH   64
#define L2E   1.44269504088896340736f

typedef __attribute__((ext_vector_type(8))) short bf16x8;
typedef __attribute__((ext_vector_type(4))) float floatx4;

__device__ __forceinline__ unsigned short f2bf(float f) {
  union { float f; unsigned int u; } v; v.f = f;
  unsigned int u = v.u;
  u += 0x7fffu + ((u >> 16) & 1u);   // RNE
  return (unsigned short)(u >> 16);
}

__device__ __forceinline__ unsigned int pk2bf(float a, float b) {
  __hip_bfloat162 h = __float22bfloat162_rn(float2{a, b});
  union { __hip_bfloat162 h; unsigned int u; } cv;
  cv.h = h;
  return cv.u;
}

__device__ __forceinline__ bf16x8 ldbf8(const unsigned short* p) {
  return *(const bf16x8*)p;
}

// XCD-aware bijective work swizzle (nwg % 8 == 0).
__device__ __forceinline__ int xcd_swz(int lin, int nwg) {
  return (lin & 7) * (nwg >> 3) + (lin >> 3);
}

// async global->LDS, 16B per lane. LDS dest = wave-uniform base + lane*16.
__device__ __forceinline__ void gload_lds16(const void* g, void* l) {
  __builtin_amdgcn_global_load_lds(
      (const __attribute__((address_space(1))) void*)g,
      (__attribute__((address_space(3))) void*)l, 16, 0, 0);
}

// ---------------------------------------------------------------------------
// Kernel 0: convert W matrices to bf16. Wq rows pre-scaled by log2(e) so the
// QK^T MFMA emits E directly in log2 units.
// ---------------------------------------------------------------------------
__global__ __launch_bounds__(256) void wconv_kernel(
    const float* __restrict__ Wq, const float* __restrict__ Wk,
    const float* __restrict__ Wv, unsigned short* __restrict__ Wb) {
  const int idx = blockIdx.x * 256 + threadIdx.x;   // < 98304
  float v;
  if (idx < 64 * CH)            v = Wq[idx] * L2E;
  else if (idx < 128 * CH)      v = Wk[idx - 64 * CH];
  else                          v = Wv[idx - 128 * CH];
  Wb[idx] = f2bf(v);
}

// ---------------------------------------------------------------------------
// Kernel 1: QKV projection GEMM. THIS ROUND: double-buffered xtile (64 KB,
// exactly the static LDS cap) so the gload_lds DMA for kb+1 overlaps the
// MFMA/repack compute of kb instead of being drained cold by the barrier
// (~900 cyc exposed x 8 iters before). One barrier per kb (was 2).
// Source rotation + read indexing unchanged (verified).
// ---------------------------------------------------------------------------
__global__ __launch_bounds__(256) void proj_kernel(
    const float* __restrict__ xq, const float* __restrict__ xk,
    const float* __restrict__ xv, const unsigned short* __restrict__ Wb,
    const float* __restrict__ bq, const float* __restrict__ bk,
    const float* __restrict__ bv,
    unsigned short* __restrict__ Qb, unsigned short* __restrict__ Kb,
    unsigned short* __restrict__ Vb) {
  __shared__ __attribute__((aligned(16))) float xtile[2][32][256];  // 64 KB
  const int t    = threadIdx.x;
  const int lane = t & 63;
  const int w    = t >> 6;
  const int l15  = lane & 15;
  const int quad = lane >> 4;
  const int b    = blockIdx.y;
  const int pxbase = blockIdx.x * 256;
  const int z    = blockIdx.z;

  const float* X; const float* bt; int dbase; int wbase;
  if (z == 0)      { X = xq; bt = bq; dbase = 0;            wbase = 0; }
  else if (z == 1) { X = xk; bt = bk; dbase = 0;            wbase = 64; }
  else             { X = xv; bt = bv; dbase = (z - 2) * 64; wbase = 128 + (z - 2) * 64; }

  floatx4 acc[4][4];
#pragma unroll
  for (int mt = 0; mt < 4; ++mt)
#pragma unroll
    for (int nt = 0; nt < 4; ++nt)
      acc[mt][nt] = (floatx4){0.f, 0.f, 0.f, 0.f};

  const float* xb0 = X + (size_t)b * CH * NPIX + pxbase;

  // per-lane source column (pre-rotated so LDS write stays linear)
  // row-local rotation: rot = 8*(cloc/8) floats; reads add it back.
  // prologue: stage kb=0 into buf 0
#pragma unroll
  for (int i = 0; i < 8; ++i) {
    const int cloc = w + i * 4;
    const int rot  = (cloc >> 3) << 3;
    const int colf = ((lane << 2) - rot) & 255;
    gload_lds16(xb0 + (size_t)cloc * NPIX + colf, &xtile[0][cloc][0]);
  }
  __syncthreads();

  int cur = 0;
  for (int kb = 0; kb < 8; ++kb) {
    // issue next-kb DMA into the other buffer (overlaps this kb's compute)
    if (kb < 7) {
#pragma unroll
      for (int i = 0; i < 8; ++i) {
        const int cloc = w + i * 4;
        const int rot  = (cloc >> 3) << 3;
        const int colf = ((lane << 2) - rot) & 255;
        gload_lds16(xb0 + (size_t)((kb + 1) * 32 + cloc) * NPIX + colf,
                    &xtile[cur ^ 1][cloc][0]);
      }
    }

#pragma unroll
    for (int nt = 0; nt < 4; ++nt) {
      // B fragment: pixel = w*64 + nt*16 + l15, k = quad*8 + j
      const int pxl = w * 64 + nt * 16 + l15;
      float f[8];
#pragma unroll
      for (int j = 0; j < 8; ++j) {
        const int row = quad * 8 + j;
        f[j] = xtile[cur][row][(pxl + ((row >> 3) << 3)) & 255];
      }
      union { bf16x8 v; unsigned int u[4]; } bb;
      bb.u[0] = pk2bf(f[0], f[1]);
      bb.u[1] = pk2bf(f[2], f[3]);
      bb.u[2] = pk2bf(f[4], f[5]);
      bb.u[3] = pk2bf(f[6], f[7]);
#pragma unroll
      for (int mt = 0; mt < 4; ++mt) {
        const bf16x8 aA =
            ldbf8(Wb + (size_t)(wbase + mt * 16 + l15) * CH + kb * 32 + quad * 8);
        acc[mt][nt] =
            __builtin_amdgcn_mfma_f32_16x16x32_bf16(aA, bb.v, acc[mt][nt], 0, 0, 0);
      }
    }
    __syncthreads();   // drains next-kb DMA; guards cur-buf reuse
    cur ^= 1;
  }

  // epilogue: C-layout col=l15 (pixel), row=quad*4+r (outch)
  float4 bias4[4];
#pragma unroll
  for (int mt = 0; mt < 4; ++mt)
    bias4[mt] = *(const float4*)&bt[dbase + mt * 16 + quad * 4];
  if (z == 0) {
#pragma unroll
    for (int mt = 0; mt < 4; ++mt) {
      bias4[mt].x *= L2E; bias4[mt].y *= L2E;
      bias4[mt].z *= L2E; bias4[mt].w *= L2E;
    }
  }

  if (z >= 2) {
    // V layout [b][c][pixel]
#pragma unroll
    for (int mt = 0; mt < 4; ++mt)
#pragma unroll
      for (int nt = 0; nt < 4; ++nt) {
        const int px = pxbase + w * 64 + nt * 16 + l15;
#pragma unroll
        for (int r = 0; r < 4; ++r) {
          const int c = dbase + mt * 16 + quad * 4 + r;
          Vb[((size_t)b * CH + c) * NPIX + px] =
              f2bf(acc[mt][nt][r] + ((const float*)&bias4[mt])[r]);
        }
      }
  } else {
    // Q/K layout [b][pixel][d]
    unsigned short* Ob = (z == 0) ? Qb : Kb;
#pragma unroll
    for (int mt = 0; mt < 4; ++mt)
#pragma unroll
      for (int nt = 0; nt < 4; ++nt) {
        const int px = pxbase + w * 64 + nt * 16 + l15;
        uint2 qp;
        qp.x = pk2bf(acc[mt][nt][0] + ((const float*)&bias4[mt])[0],
                     acc[mt][nt][1] + ((const float*)&bias4[mt])[1]);
        qp.y = pk2bf(acc[mt][nt][2] + ((const float*)&bias4[mt])[2],
                     acc[mt][nt][3] + ((const float*)&bias4[mt])[3]);
        *(uint2*)&Ob[((size_t)b * NPIX + px) * DQH + mt * 16 + quad * 4] = qp;
      }
  }
}

// ---------------------------------------------------------------------------
// Kernel 2: per-row softmax stats, max-free in log2 domain (unchanged from
// the 755.8-us build).
// ---------------------------------------------------------------------------
__global__ __launch_bounds__(256) void pass1_kernel(
    const unsigned short* __restrict__ Qb, const unsigned short* __restrict__ Kb,
    float* __restrict__ Srow) {
  const int t    = threadIdx.x;
  const int lane = t & 63;
  const int w    = t >> 6;
  const int l15  = lane & 15;
  const int quad = lane >> 4;
  const int lin  = blockIdx.x + (blockIdx.y << 6);      // grid (64,16)
  const int swz  = xcd_swz(lin, 64 * BATCH);
  const int b     = swz >> 6;
  const int jbase = (swz & 63) * 64 + w * 16;

  const unsigned short* qrow = Qb + ((size_t)b * NPIX + jbase + l15) * DQH;
  const bf16x8 qA0 = ldbf8(qrow + quad * 8);
  const bf16x8 qA1 = ldbf8(qrow + 32 + quad * 8);

  float lsum[4] = {0.f, 0.f, 0.f, 0.f};

  const unsigned short* kbase = Kb + (size_t)b * NPIX * DQH;

  bf16x8 kC[4][2], kN[4][2];
#pragma unroll
  for (int nt = 0; nt < 4; ++nt) {
    const unsigned short* krow = kbase + (size_t)(nt * 16 + l15) * DQH;
    kC[nt][0] = ldbf8(krow + quad * 8);
    kC[nt][1] = ldbf8(krow + 32 + quad * 8);
  }

  for (int ib = 0; ib < NPIX; ib += 64) {
    const int in = (ib + 64) & (NPIX - 1);   // wraps on last iter (unused)
#pragma unroll
    for (int nt = 0; nt < 4; ++nt) {
      const unsigned short* krow = kbase + (size_t)(in + nt * 16 + l15) * DQH;
      kN[nt][0] = ldbf8(krow + quad * 8);
      kN[nt][1] = ldbf8(krow + 32 + quad * 8);
    }
#pragma unroll
    for (int nt = 0; nt < 4; ++nt) {
      floatx4 a = {0.f, 0.f, 0.f, 0.f};
      a = __builtin_amdgcn_mfma_f32_16x16x32_bf16(qA0, kC[nt][0], a, 0, 0, 0);
      a = __builtin_amdgcn_mfma_f32_16x16x32_bf16(qA1, kC[nt][1], a, 0, 0, 0);
#pragma unroll
      for (int r = 0; r < 4; ++r) lsum[r] += exp2f(a[r]);
    }
#pragma unroll
    for (int nt = 0; nt < 4; ++nt) {
      kC[nt][0] = kN[nt][0];
      kC[nt][1] = kN[nt][1];
    }
  }

#pragma unroll
  for (int r = 0; r < 4; ++r) {
    float s = lsum[r];
    s += __shfl_xor(s, 1);
    s += __shfl_xor(s, 2);
    s += __shfl_xor(s, 4);
    s += __shfl_xor(s, 8);
    if (l15 == 0)
      Srow[(size_t)b * NPIX + jbase + quad * 4 + r] = log2f(s);
  }
}

// ---------------------------------------------------------------------------
// Kernel 3: out[:, i-tile] = sum_j 2^{E'[j,i]-s'_j} * v[:,j].
// EXACT restore of the twice-measured 325-us structure (r1/r3): Q j-tile in
// LDS (dbuf, T14 reg-carry), Plds dbuf, ONE barrier per 64-j step, V loads
// inline in PV, 40 MFMA per wave per barrier. Do not touch.
// ---------------------------------------------------------------------------
__global__ __launch_bounds__(256, 4) void pass2_kernel(
    const unsigned short* __restrict__ Qb, const unsigned short* __restrict__ Kb,
    const unsigned short* __restrict__ Vb, const float* __restrict__ Srow,
    float* __restrict__ out) {
  __shared__ __attribute__((aligned(16))) unsigned short Plds[2][64][72];  // 18 KB
  __shared__ __attribute__((aligned(16))) unsigned short Qlds[2][64][72];  // 18 KB
  const int t    = threadIdx.x;
  const int lane = t & 63;
  const int w    = t >> 6;
  const int l15  = lane & 15;
  const int quad = lane >> 4;
  const int lin  = blockIdx.x + (blockIdx.y << 6);      // grid (64,16)
  const int swz  = xcd_swz(lin, 64 * BATCH);
  const int b     = swz >> 6;
  const int ibase = (swz & 63) * 64;

  const unsigned short* krow = Kb + ((size_t)b * NPIX + ibase + w * 16 + l15) * DQH;
  const bf16x8 kB0 = ldbf8(krow + quad * 8);
  const bf16x8 kB1 = ldbf8(krow + 32 + quad * 8);

  floatx4 accO[4][4];
#pragma unroll
  for (int mt = 0; mt < 4; ++mt)
#pragma unroll
    for (int nt = 0; nt < 4; ++nt)
      accO[mt][nt] = (floatx4){0.f, 0.f, 0.f, 0.f};

  const float* sp          = Srow + (size_t)b * NPIX;
  const unsigned short* qb = Qb + (size_t)b * NPIX * DQH;
  const unsigned short* vb = Vb + (size_t)b * CH * NPIX;

  // Q staging geometry: 256 threads cover 64 rows x 128 B (two 16B segs each)
  const int srow = t >> 3;          // 0..31 (and +32)
  const int sseg = t & 7;           // 16B segment within the 128B row

  // prologue: stage Q tile for jb = 0 into Qlds[0]
  {
    const unsigned short* qsrc = qb + (size_t)srow * DQH + sseg * 8;
    *(uint4*)&Qlds[0][srow][sseg * 8]      = *(const uint4*)qsrc;
    *(uint4*)&Qlds[0][srow + 32][sseg * 8] = *(const uint4*)(qsrc + 32 * DQH);
  }
  __syncthreads();

  int cur = 0;
  for (int jb = 0; jb < NPIX; jb += 64) {
    // T14: issue next-tile Q global loads now; LDS-write them after E-phase
    const int jn = (jb + 64) & (NPIX - 1);
    const unsigned short* qsrc = qb + (size_t)(jn + srow) * DQH + sseg * 8;
    const uint4 d0 = *(const uint4*)qsrc;
    const uint4 d1 = *(const uint4*)(qsrc + 32 * DQH);

    // E + P for 64 j rows (this wave's 16-i strip), Q frags from Qlds[cur]
#pragma unroll
    for (int jt = 0; jt < 4; ++jt) {
      const bf16x8 q0 = ldbf8(&Qlds[cur][jt * 16 + l15][quad * 8]);
      const bf16x8 q1 = ldbf8(&Qlds[cur][jt * 16 + l15][32 + quad * 8]);
      floatx4 a = {0.f, 0.f, 0.f, 0.f};
      a = __builtin_amdgcn_mfma_f32_16x16x32_bf16(q0, kB0, a, 0, 0, 0);
      a = __builtin_amdgcn_mfma_f32_16x16x32_bf16(q1, kB1, a, 0, 0, 0);
      const float4 s4 = *(const float4*)&sp[jb + jt * 16 + quad * 4];
      uint2 pk;
      pk.x = pk2bf(exp2f(a[0] - s4.x), exp2f(a[1] - s4.y));
      pk.y = pk2bf(exp2f(a[2] - s4.z), exp2f(a[3] - s4.w));
      *(uint2*)&Plds[cur][w * 16 + l15][jt * 16 + quad * 4] = pk;
    }

    // stage writes for the NEXT iteration (other buffer; no reader yet)
    *(uint4*)&Qlds[cur ^ 1][srow][sseg * 8]      = d0;
    *(uint4*)&Qlds[cur ^ 1][srow + 32][sseg * 8] = d1;

    __syncthreads();   // P[cur] visible; Q[cur^1] staged; single barrier/iter

    // PV: acc[c, i] += V[c, jb..jb+64] * P  (reads Plds[cur] only)
#pragma unroll
    for (int ks = 0; ks < 2; ++ks) {
      bf16x8 pB[4];
#pragma unroll
      for (int nt = 0; nt < 4; ++nt)
        pB[nt] = ldbf8(&Plds[cur][nt * 16 + l15][ks * 32 + quad * 8]);
#pragma unroll
      for (int mt = 0; mt < 4; ++mt) {
        const unsigned short* vrow =
            vb + (size_t)(w * 64 + mt * 16 + l15) * NPIX + jb + ks * 32;
        const bf16x8 vA = ldbf8(vrow + quad * 8);
#pragma unroll
        for (int nt = 0; nt < 4; ++nt)
          accO[mt][nt] =
              __builtin_amdgcn_mfma_f32_16x16x32_bf16(vA, pB[nt], accO[mt][nt], 0, 0, 0);
      }
    }
    cur ^= 1;
  }

#pragma unroll
  for (int mt = 0; mt < 4; ++mt) {
#pragma unroll
    for (int nt = 0; nt < 4; ++nt) {
#pragma unroll
      for (int r = 0; r < 4; ++r) {
        const int c = w * 64 + mt * 16 + quad * 4 + r;
        const int i = ibase + nt * 16 + l15;
        out[((size_t)b * CH + c) * NPIX + i] = accO[mt][nt][r];
      }
    }
  }
}

// ---------------------------------------------------------------------------
extern "C" void kernel_launch(void* const* d_in, const int* in_sizes, int n_in,
                              void* d_out, int out_size, void* d_ws, size_t ws_size,
                              hipStream_t stream) {
  (void)in_sizes; (void)n_in; (void)out_size; (void)ws_size;
  const float* xq = (const float*)d_in[0];
  const float* xk = (const float*)d_in[1];
  const float* xv = (const float*)d_in[2];
  const float* Wq = (const float*)d_in[3];
  const float* bq = (const float*)d_in[4];
  const float* Wk = (const float*)d_in[5];
  const float* bk = (const float*)d_in[6];
  const float* Wv = (const float*)d_in[7];
  const float* bv = (const float*)d_in[8];
  float* out = (float*)d_out;

  // workspace layout (bytes):
  //   Qb bf16 [16][4096][64]   @ 0          (8 MiB)   (pre-scaled by log2(e))
  //   Kb bf16 [16][4096][64]   @ 8 MiB      (8 MiB)
  //   Vb bf16 [16][256][4096]  @ 16 MiB     (32 MiB)
  //   Srow f32 [16][4096]      @ 48 MiB     (256 KiB) (log2-domain LSE)
  //   Wb bf16 [384][256]       @ 48.25 MiB  (192 KiB)
  char* ws = (char*)d_ws;
  const size_t qk_bytes = (size_t)BATCH * NPIX * DQH * 2;   // 8 MiB
  const size_t v_bytes  = (size_t)BATCH * CH * NPIX * 2;    // 32 MiB
  const size_t s_bytes  = (size_t)BATCH * NPIX * 4;         // 256 KiB
  unsigned short* Qb = (unsigned short*)(ws);
  unsigned short* Kb = (unsigned short*)(ws + qk_bytes);
  unsigned short* Vb = (unsigned short*)(ws + 2 * qk_bytes);
  float* Srow        = (float*)(ws + 2 * qk_bytes + v_bytes);
  unsigned short* Wb = (unsigned short*)(ws + 2 * qk_bytes + v_bytes + s_bytes);

  wconv_kernel<<<dim3(384), 256, 0, stream>>>(Wq, Wk, Wv, Wb);
  proj_kernel<<<dim3(16, 16, 6), 256, 0, stream>>>(xq, xk, xv, Wb, bq, bk, bv,
                                                   Qb, Kb, Vb);
  pass1_kernel<<<dim3(64, 16), 256, 0, stream>>>(Qb, Kb, Srow);
  pass2_kernel<<<dim3(64, 16), 256, 0, stream>>>(Qb, Kb, Vb, Srow, out);
}

// Round 8
// 697.389 us; speedup vs baseline: 1.5551x; 1.0883x over previous
//
#include <hip/hip_runtime.h>
#include <hip/hip_bf16.h>
#include <stddef.h>

#define BATCH 16
#define CH    256
#define NPIX  4096
#define DQH   64
#define L2E   1.44269504088896340736f

typedef __attribute__((ext_vector_type(8))) short bf16x8;
typedef __attribute__((ext_vector_type(4))) float floatx4;

__device__ __forceinline__ unsigned short f2bf(float f) {
  union { float f; unsigned int u; } v; v.f = f;
  unsigned int u = v.u;
  u += 0x7fffu + ((u >> 16) & 1u);   // RNE
  return (unsigned short)(u >> 16);
}

__device__ __forceinline__ unsigned int pk2bf(float a, float b) {
  __hip_bfloat162 h = __float22bfloat162_rn(float2{a, b});
  union { __hip_bfloat162 h; unsigned int u; } cv;
  cv.h = h;
  return cv.u;
}

__device__ __forceinline__ bf16x8 ldbf8(const unsigned short* p) {
  return *(const bf16x8*)p;
}

// XCD-aware bijective work swizzle (nwg % 8 == 0).
__device__ __forceinline__ int xcd_swz(int lin, int nwg) {
  return (lin & 7) * (nwg >> 3) + (lin >> 3);
}

// async global->LDS, 16B per lane. LDS dest = wave-uniform base + lane*16.
__device__ __forceinline__ void gload_lds16(const void* g, void* l) {
  __builtin_amdgcn_global_load_lds(
      (const __attribute__((address_space(1))) void*)g,
      (__attribute__((address_space(3))) void*)l, 16, 0, 0);
}

// ---------------------------------------------------------------------------
// Kernel 0: convert W matrices to bf16. Wq rows pre-scaled by log2(e) so the
// QK^T MFMA emits E directly in log2 units.
// ---------------------------------------------------------------------------
__global__ __launch_bounds__(256) void wconv_kernel(
    const float* __restrict__ Wq, const float* __restrict__ Wk,
    const float* __restrict__ Wv, unsigned short* __restrict__ Wb) {
  const int idx = blockIdx.x * 256 + threadIdx.x;   // < 98304
  float v;
  if (idx < 64 * CH)            v = Wq[idx] * L2E;
  else if (idx < 128 * CH)      v = Wk[idx - 64 * CH];
  else                          v = Wv[idx - 128 * CH];
  Wb[idx] = f2bf(v);
}

// ---------------------------------------------------------------------------
// Kernel 1: QKV projection GEMM (r3 version: gload_lds staging, 32 KB,
// source-rotated bank fix; the 755.8-us build).
// ---------------------------------------------------------------------------
__global__ __launch_bounds__(256) void proj_kernel(
    const float* __restrict__ xq, const float* __restrict__ xk,
    const float* __restrict__ xv, const unsigned short* __restrict__ Wb,
    const float* __restrict__ bq, const float* __restrict__ bk,
    const float* __restrict__ bv,
    unsigned short* __restrict__ Qb, unsigned short* __restrict__ Kb,
    unsigned short* __restrict__ Vb) {
  __shared__ __attribute__((aligned(16))) float xtile[32][256];  // 32 KB
  const int t    = threadIdx.x;
  const int lane = t & 63;
  const int w    = t >> 6;
  const int l15  = lane & 15;
  const int quad = lane >> 4;
  const int b    = blockIdx.y;
  const int pxbase = blockIdx.x * 256;
  const int z    = blockIdx.z;

  const float* X; const float* bt; int dbase; int wbase;
  if (z == 0)      { X = xq; bt = bq; dbase = 0;            wbase = 0; }
  else if (z == 1) { X = xk; bt = bk; dbase = 0;            wbase = 64; }
  else             { X = xv; bt = bv; dbase = (z - 2) * 64; wbase = 128 + (z - 2) * 64; }

  floatx4 acc[4][4];
#pragma unroll
  for (int mt = 0; mt < 4; ++mt)
#pragma unroll
    for (int nt = 0; nt < 4; ++nt)
      acc[mt][nt] = (floatx4){0.f, 0.f, 0.f, 0.f};

  const float* xb0 = X + (size_t)b * CH * NPIX + pxbase;

  for (int kb = 0; kb < 8; ++kb) {
    // stage 32 rows x 256 px fp32 -> LDS via async DMA; source pre-rotated
#pragma unroll
    for (int i = 0; i < 8; ++i) {
      const int cloc = w + i * 4;                       // wave-uniform row
      const int rot  = (cloc >> 3) << 3;                // 8*(row/8) floats
      const int colf = ((lane << 2) - rot) & 255;       // per-lane source col
      gload_lds16(xb0 + (size_t)(kb * 32 + cloc) * NPIX + colf,
                  &xtile[cloc][0]);
    }
    __syncthreads();   // drains vmcnt -> xtile ready

#pragma unroll
    for (int nt = 0; nt < 4; ++nt) {
      // B fragment: pixel = w*64 + nt*16 + l15, k = quad*8 + j
      const int pxl = w * 64 + nt * 16 + l15;
      float f[8];
#pragma unroll
      for (int j = 0; j < 8; ++j) {
        const int row = quad * 8 + j;
        f[j] = xtile[row][(pxl + ((row >> 3) << 3)) & 255];
      }
      union { bf16x8 v; unsigned int u[4]; } bb;
      bb.u[0] = pk2bf(f[0], f[1]);
      bb.u[1] = pk2bf(f[2], f[3]);
      bb.u[2] = pk2bf(f[4], f[5]);
      bb.u[3] = pk2bf(f[6], f[7]);
#pragma unroll
      for (int mt = 0; mt < 4; ++mt) {
        const bf16x8 aA =
            ldbf8(Wb + (size_t)(wbase + mt * 16 + l15) * CH + kb * 32 + quad * 8);
        acc[mt][nt] =
            __builtin_amdgcn_mfma_f32_16x16x32_bf16(aA, bb.v, acc[mt][nt], 0, 0, 0);
      }
    }
    __syncthreads();
  }

  // epilogue: C-layout col=l15 (pixel), row=quad*4+r (outch)
  float4 bias4[4];
#pragma unroll
  for (int mt = 0; mt < 4; ++mt)
    bias4[mt] = *(const float4*)&bt[dbase + mt * 16 + quad * 4];
  if (z == 0) {
#pragma unroll
    for (int mt = 0; mt < 4; ++mt) {
      bias4[mt].x *= L2E; bias4[mt].y *= L2E;
      bias4[mt].z *= L2E; bias4[mt].w *= L2E;
    }
  }

  if (z >= 2) {
    // V layout [b][c][pixel]
#pragma unroll
    for (int mt = 0; mt < 4; ++mt)
#pragma unroll
      for (int nt = 0; nt < 4; ++nt) {
        const int px = pxbase + w * 64 + nt * 16 + l15;
#pragma unroll
        for (int r = 0; r < 4; ++r) {
          const int c = dbase + mt * 16 + quad * 4 + r;
          Vb[((size_t)b * CH + c) * NPIX + px] =
              f2bf(acc[mt][nt][r] + ((const float*)&bias4[mt])[r]);
        }
      }
  } else {
    // Q/K layout [b][pixel][d]
    unsigned short* Ob = (z == 0) ? Qb : Kb;
#pragma unroll
    for (int mt = 0; mt < 4; ++mt)
#pragma unroll
      for (int nt = 0; nt < 4; ++nt) {
        const int px = pxbase + w * 64 + nt * 16 + l15;
        uint2 qp;
        qp.x = pk2bf(acc[mt][nt][0] + ((const float*)&bias4[mt])[0],
                     acc[mt][nt][1] + ((const float*)&bias4[mt])[1]);
        qp.y = pk2bf(acc[mt][nt][2] + ((const float*)&bias4[mt])[2],
                     acc[mt][nt][3] + ((const float*)&bias4[mt])[3]);
        *(uint2*)&Ob[((size_t)b * NPIX + px) * DQH + mt * 16 + quad * 4] = qp;
      }
  }
}

// ---------------------------------------------------------------------------
// Kernel 2: per-row softmax stats, max-free in log2 domain (unchanged).
// ---------------------------------------------------------------------------
__global__ __launch_bounds__(256) void pass1_kernel(
    const unsigned short* __restrict__ Qb, const unsigned short* __restrict__ Kb,
    float* __restrict__ Srow) {
  const int t    = threadIdx.x;
  const int lane = t & 63;
  const int w    = t >> 6;
  const int l15  = lane & 15;
  const int quad = lane >> 4;
  const int lin  = blockIdx.x + (blockIdx.y << 6);      // grid (64,16)
  const int swz  = xcd_swz(lin, 64 * BATCH);
  const int b     = swz >> 6;
  const int jbase = (swz & 63) * 64 + w * 16;

  const unsigned short* qrow = Qb + ((size_t)b * NPIX + jbase + l15) * DQH;
  const bf16x8 qA0 = ldbf8(qrow + quad * 8);
  const bf16x8 qA1 = ldbf8(qrow + 32 + quad * 8);

  float lsum[4] = {0.f, 0.f, 0.f, 0.f};

  const unsigned short* kbase = Kb + (size_t)b * NPIX * DQH;

  bf16x8 kC[4][2], kN[4][2];
#pragma unroll
  for (int nt = 0; nt < 4; ++nt) {
    const unsigned short* krow = kbase + (size_t)(nt * 16 + l15) * DQH;
    kC[nt][0] = ldbf8(krow + quad * 8);
    kC[nt][1] = ldbf8(krow + 32 + quad * 8);
  }

  for (int ib = 0; ib < NPIX; ib += 64) {
    const int in = (ib + 64) & (NPIX - 1);   // wraps on last iter (unused)
#pragma unroll
    for (int nt = 0; nt < 4; ++nt) {
      const unsigned short* krow = kbase + (size_t)(in + nt * 16 + l15) * DQH;
      kN[nt][0] = ldbf8(krow + quad * 8);
      kN[nt][1] = ldbf8(krow + 32 + quad * 8);
    }
#pragma unroll
    for (int nt = 0; nt < 4; ++nt) {
      floatx4 a = {0.f, 0.f, 0.f, 0.f};
      a = __builtin_amdgcn_mfma_f32_16x16x32_bf16(qA0, kC[nt][0], a, 0, 0, 0);
      a = __builtin_amdgcn_mfma_f32_16x16x32_bf16(qA1, kC[nt][1], a, 0, 0, 0);
#pragma unroll
      for (int r = 0; r < 4; ++r) lsum[r] += exp2f(a[r]);
    }
#pragma unroll
    for (int nt = 0; nt < 4; ++nt) {
      kC[nt][0] = kN[nt][0];
      kC[nt][1] = kN[nt][1];
    }
  }

#pragma unroll
  for (int r = 0; r < 4; ++r) {
    float s = lsum[r];
    s += __shfl_xor(s, 1);
    s += __shfl_xor(s, 2);
    s += __shfl_xor(s, 4);
    s += __shfl_xor(s, 8);
    if (l15 == 0)
      Srow[(size_t)b * NPIX + jbase + quad * 4 + r] = log2f(s);
  }
}

// ---------------------------------------------------------------------------
// Kernel 3: out[:, i-tile] = sum_j 2^{E'[j,i]-s'_j} * v[:,j].
// r3 skeleton (1 barrier/iter, 40 MFMA/wave/iter) + V staged in LDS:
//  - V's A-frag was a 16-line gather (rows strided 8KB) -> ~128 L1
//    transactions per wave-iter, vmcnt-serialized in the mt loop. Now each
//    wave DMAs its PRIVATE 64-row c-strip (coalesced 128B rows) for tile
//    n+1 right after its own PV reads of tile n -> no cross-wave hazard,
//    no extra barrier; the existing barrier (one E-phase later) drains it.
//  - Vlds reads XOR-swizzled (conflict-free), swizzle pre-applied on DMA
//    source (r5-validated pattern).
//  - Qlds/Plds switch pad-72 -> swizzle-64 (r5-validated addressing) to fit
//    the 64KB static LDS cap exactly (32+16+16).
// ---------------------------------------------------------------------------
__global__ __launch_bounds__(256) void pass2_kernel(
    const unsigned short* __restrict__ Qb, const unsigned short* __restrict__ Kb,
    const unsigned short* __restrict__ Vb, const float* __restrict__ Srow,
    float* __restrict__ out) {
  __shared__ __attribute__((aligned(16))) unsigned short Vlds[256][64];    // 32 KB
  __shared__ __attribute__((aligned(16))) unsigned short Qlds[2][64][64];  // 16 KB
  __shared__ __attribute__((aligned(16))) unsigned short Plds[2][64][64];  // 16 KB
  const int t    = threadIdx.x;
  const int lane = t & 63;
  const int w    = t >> 6;
  const int l15  = lane & 15;
  const int quad = lane >> 4;
  const int lin  = blockIdx.x + (blockIdx.y << 6);      // grid (64,16)
  const int swz  = xcd_swz(lin, 64 * BATCH);
  const int b     = swz >> 6;
  const int ibase = (swz & 63) * 64;

  const unsigned short* krow = Kb + ((size_t)b * NPIX + ibase + w * 16 + l15) * DQH;
  const bf16x8 kB0 = ldbf8(krow + quad * 8);
  const bf16x8 kB1 = ldbf8(krow + 32 + quad * 8);

  floatx4 accO[4][4];
#pragma unroll
  for (int mt = 0; mt < 4; ++mt)
#pragma unroll
    for (int nt = 0; nt < 4; ++nt)
      accO[mt][nt] = (floatx4){0.f, 0.f, 0.f, 0.f};

  const float* sp          = Srow + (size_t)b * NPIX;
  const unsigned short* qb = Qb + (size_t)b * NPIX * DQH;
  const unsigned short* vb = Vb + (size_t)b * CH * NPIX;

  // Q staging geometry: thread t covers rows t>>3 and (t>>3)+32, seg t&7.
  // Swizzled byte col; (srow+32)&7 == srow&7 so one sswz serves both rows.
  const int srow = t >> 3;          // 0..31
  const int sseg = t & 7;
  const int sswz = (sseg * 16) ^ ((srow & 7) << 4);

  // V DMA geometry: wave w owns c-strip [w*64, w*64+64); 8 shots x 8 rows.
  // Source col pre-swizzled so the linear LDS write + XOR read compose.
  const int vrow0 = w * 64 + (lane >> 3);               // + s*8
  const int vcol  = (((lane & 7) ^ (lane >> 3)) << 3);  // shorts

  // prologue: stage Q tile jb=0 (buf 0) and V tile jb=0 (own strip)
  {
    const unsigned short* qsrc = qb + (size_t)srow * DQH + sseg * 8;
    *(uint4*)((char*)&Qlds[0][srow][0] + sswz)      = *(const uint4*)qsrc;
    *(uint4*)((char*)&Qlds[0][srow + 32][0] + sswz) = *(const uint4*)(qsrc + 32 * DQH);
  }
#pragma unroll
  for (int s = 0; s < 8; ++s)
    gload_lds16(vb + (size_t)(vrow0 + s * 8) * NPIX + vcol,
                &Vlds[w * 64 + s * 8][0]);
  __syncthreads();   // drains V DMA; Q visible

  int cur = 0;
  for (int jb = 0; jb < NPIX; jb += 64) {
    const int jn = (jb + 64) & (NPIX - 1);   // wraps on last iter (unused)

    // T14: next-tile Q global loads -> regs (LDS-write after E phase)
    const unsigned short* qsrc = qb + (size_t)(jn + srow) * DQH + sseg * 8;
    const uint4 d0 = *(const uint4*)qsrc;
    const uint4 d1 = *(const uint4*)(qsrc + 32 * DQH);

    // hoisted Srow loads for this tile
    float4 s4[4];
#pragma unroll
    for (int jt = 0; jt < 4; ++jt)
      s4[jt] = *(const float4*)&sp[jb + jt * 16 + quad * 4];

    // ---- E phase: P[i = w*16 strip][j = 0..64] ----
#pragma unroll
    for (int jt = 0; jt < 4; ++jt) {
      const int qr = jt * 16 + l15;
      const int qx = (qr & 7) << 4;
      const bf16x8 q0 =
          *(const bf16x8*)((const char*)&Qlds[cur][qr][0] + ((quad * 16) ^ qx));
      const bf16x8 q1 =
          *(const bf16x8*)((const char*)&Qlds[cur][qr][0] + ((64 + quad * 16) ^ qx));
      floatx4 a = {0.f, 0.f, 0.f, 0.f};
      a = __builtin_amdgcn_mfma_f32_16x16x32_bf16(q0, kB0, a, 0, 0, 0);
      a = __builtin_amdgcn_mfma_f32_16x16x32_bf16(q1, kB1, a, 0, 0, 0);
      uint2 pk;
      pk.x = pk2bf(exp2f(a[0] - s4[jt].x), exp2f(a[1] - s4[jt].y));
      pk.y = pk2bf(exp2f(a[2] - s4[jt].z), exp2f(a[3] - s4[jt].w));
      const int pr = w * 16 + l15;
      *(uint2*)((char*)&Plds[cur][pr][0] +
                ((jt * 32 + quad * 8) ^ ((pr & 7) << 4))) = pk;
    }

    // stage next Q tile into the other buffer (no reader until after bar)
    *(uint4*)((char*)&Qlds[cur ^ 1][srow][0] + sswz)      = d0;
    *(uint4*)((char*)&Qlds[cur ^ 1][srow + 32][0] + sswz) = d1;

    __syncthreads();   // P[cur] ready; Q[cur^1] staged; V(jb) DMA drained

    // ---- PV: acc[c,i] += V[c, jb..jb+64] * P (V from LDS, swizzled) ----
#pragma unroll
    for (int ks = 0; ks < 2; ++ks) {
      bf16x8 pB[4];
#pragma unroll
      for (int nt = 0; nt < 4; ++nt) {
        const int br = nt * 16 + l15;
        pB[nt] = *(const bf16x8*)((const char*)&Plds[cur][br][0] +
                                  ((ks * 64 + quad * 16) ^ ((br & 7) << 4)));
      }
#pragma unroll
      for (int mt = 0; mt < 4; ++mt) {
        const int vr = w * 64 + mt * 16 + l15;
        const bf16x8 vA =
            *(const bf16x8*)((const char*)&Vlds[vr][0] +
                             ((ks * 64 + quad * 16) ^ ((l15 & 7) << 4)));
#pragma unroll
        for (int nt = 0; nt < 4; ++nt)
          accO[mt][nt] = __builtin_amdgcn_mfma_f32_16x16x32_bf16(
              vA, pB[nt], accO[mt][nt], 0, 0, 0);
      }
    }

    // issue V DMA for next tile into THIS WAVE's private strip.
    // sched_barrier pins it after the PV Vlds reads (no hoist).
    __builtin_amdgcn_sched_barrier(0);
#pragma unroll
    for (int s = 0; s < 8; ++s)
      gload_lds16(vb + (size_t)(vrow0 + s * 8) * NPIX + jn + vcol,
                  &Vlds[w * 64 + s * 8][0]);

    cur ^= 1;
  }

#pragma unroll
  for (int mt = 0; mt < 4; ++mt) {
#pragma unroll
    for (int nt = 0; nt < 4; ++nt) {
#pragma unroll
      for (int r = 0; r < 4; ++r) {
        const int c = w * 64 + mt * 16 + quad * 4 + r;
        const int i = ibase + nt * 16 + l15;
        out[((size_t)b * CH + c) * NPIX + i] = accO[mt][nt][r];
      }
    }
  }
}

// ---------------------------------------------------------------------------
extern "C" void kernel_launch(void* const* d_in, const int* in_sizes, int n_in,
                              void* d_out, int out_size, void* d_ws, size_t ws_size,
                              hipStream_t stream) {
  (void)in_sizes; (void)n_in; (void)out_size; (void)ws_size;
  const float* xq = (const float*)d_in[0];
  const float* xk = (const float*)d_in[1];
  const float* xv = (const float*)d_in[2];
  const float* Wq = (const float*)d_in[3];
  const float* bq = (const float*)d_in[4];
  const float* Wk = (const float*)d_in[5];
  const float* bk = (const float*)d_in[6];
  const float* Wv = (const float*)d_in[7];
  const float* bv = (const float*)d_in[8];
  float* out = (float*)d_out;

  // workspace layout (bytes):
  //   Qb bf16 [16][4096][64]   @ 0          (8 MiB)   (pre-scaled by log2(e))
  //   Kb bf16 [16][4096][64]   @ 8 MiB      (8 MiB)
  //   Vb bf16 [16][256][4096]  @ 16 MiB     (32 MiB)
  //   Srow f32 [16][4096]      @ 48 MiB     (256 KiB) (log2-domain LSE)
  //   Wb bf16 [384][256]       @ 48.25 MiB  (192 KiB)
  char* ws = (char*)d_ws;
  const size_t qk_bytes = (size_t)BATCH * NPIX * DQH * 2;   // 8 MiB
  const size_t v_bytes  = (size_t)BATCH * CH * NPIX * 2;    // 32 MiB
  const size_t s_bytes  = (size_t)BATCH * NPIX * 4;         // 256 KiB
  unsigned short* Qb = (unsigned short*)(ws);
  unsigned short* Kb = (unsigned short*)(ws + qk_bytes);
  unsigned short* Vb = (unsigned short*)(ws + 2 * qk_bytes);
  float* Srow        = (float*)(ws + 2 * qk_bytes + v_bytes);
  unsigned short* Wb = (unsigned short*)(ws + 2 * qk_bytes + v_bytes + s_bytes);

  wconv_kernel<<<dim3(384), 256, 0, stream>>>(Wq, Wk, Wv, Wb);
  proj_kernel<<<dim3(16, 16, 6), 256, 0, stream>>>(xq, xk, xv, Wb, bq, bk, bv,
                                                   Qb, Kb, Vb);
  pass1_kernel<<<dim3(64, 16), 256, 0, stream>>>(Qb, Kb, Srow);
  pass2_kernel<<<dim3(64, 16), 256, 0, stream>>>(Qb, Kb, Vb, Srow, out);
}